// Round 4
// baseline (475.926 us; speedup 1.0000x reference)
//
#include <hip/hip_runtime.h>
#include <hip/hip_bf16.h>

#define TOK 8192      // B*S tokens
#define HD 2048       // hidden
#define NE 8          // experts
#define KTOP 2
#define NSLOT (TOK * KTOP)
#define NCHUNK (TOK / 256)   // 32 routing chunks

typedef __attribute__((ext_vector_type(8))) short bf16x8;
typedef __attribute__((ext_vector_type(4))) float f32x4;

// async global->LDS, 16B per lane, dest = wave-uniform base + lane*16
#define GLDS16(g, l) __builtin_amdgcn_global_load_lds( \
    (const __attribute__((address_space(1))) void*)(g), \
    (__attribute__((address_space(3))) void*)(l), 16, 0, 0)

// round-to-nearest-even fp32 -> bf16 bits
__device__ __forceinline__ unsigned short f2bf(float f) {
  union { float f; unsigned u; } v; v.f = f;
  unsigned r = v.u + 0x7fffu + ((v.u >> 16) & 1u);
  return (unsigned short)(r >> 16);
}
__device__ __forceinline__ float bf2f(unsigned short b) {
  union { unsigned u; float f; } v; v.u = ((unsigned)b) << 16;
  return v.f;
}

// ---------------- fused: router (even bids) + weight transpose-convert (odd bids) ------
__global__ __launch_bounds__(256) void route_wconv_kernel(
    const float* __restrict__ x, const float* __restrict__ Wg, const float* __restrict__ bg,
    const float* __restrict__ We,
    int* __restrict__ eidx2, float* __restrict__ gate2,
    unsigned short* __restrict__ xbf, unsigned short* __restrict__ Wt) {
  __shared__ union {
    struct { float xs[HD]; float red[4][NE]; } r;   // routex: 8.3 KB
    float tile[64][65];                             // wconv: 16.6 KB
  } sm;
  int bid = blockIdx.x;
  int tid = threadIdx.x;

  if (bid & 1) {
    // ---- wconv: We[e][k][n] -> Wt[e][n][k] bf16, 64x64 tile ----
    int i = bid >> 1;
    int e = i >> 10;                  // 1024 tiles per expert (32x32)
    int rem = i & 1023;
    int k0 = (rem >> 5) * 64, n0 = (rem & 31) * 64;
    const float* src = We + ((size_t)e * HD + k0) * HD + n0;
#pragma unroll
    for (int it = 0; it < 4; it++) {
      int f = tid + it * 256;
      int r = f >> 4, c4 = (f & 15) * 4;
      float4 v = *(const float4*)(src + (size_t)r * HD + c4);
      sm.tile[r][c4 + 0] = v.x; sm.tile[r][c4 + 1] = v.y;
      sm.tile[r][c4 + 2] = v.z; sm.tile[r][c4 + 3] = v.w;
    }
    __syncthreads();
    unsigned short* dst = Wt + ((size_t)e * HD + n0) * HD + k0;
#pragma unroll
    for (int it = 0; it < 2; it++) {
      int s = tid + it * 256;
      int n = s >> 3, k8 = (s & 7) * 8;
      union { bf16x8 v; unsigned short us[8]; } o;
#pragma unroll
      for (int j = 0; j < 8; j++) o.us[j] = f2bf(sm.tile[k8 + j][n]);
      *(bf16x8*)(dst + (size_t)n * HD + k8) = o.v;
    }
    return;
  }

  // ---- routex: x->bf16 + router (logits, softmax, top-2). No atomics. ----
  int t = bid >> 1;
  const float4* xr = (const float4*)(x + (size_t)t * HD);
  float4 a = xr[tid * 2], b = xr[tid * 2 + 1];
  union { bf16x8 v; unsigned short s[8]; } o;
  o.s[0] = f2bf(a.x); o.s[1] = f2bf(a.y); o.s[2] = f2bf(a.z); o.s[3] = f2bf(a.w);
  o.s[4] = f2bf(b.x); o.s[5] = f2bf(b.y); o.s[6] = f2bf(b.z); o.s[7] = f2bf(b.w);
  *(bf16x8*)(xbf + (size_t)t * HD + tid * 8) = o.v;
  *(float4*)(sm.r.xs + tid * 8) = a;
  *(float4*)(sm.r.xs + tid * 8 + 4) = b;
  __syncthreads();

  float acc[NE];
#pragma unroll
  for (int e = 0; e < NE; e++) acc[e] = 0.f;
#pragma unroll
  for (int i = 0; i < HD / 256; i++) {
    int k = tid + i * 256;               // consecutive lanes -> consecutive Wg rows
    float v = sm.r.xs[k];
    const float4* wr = (const float4*)(Wg + (size_t)k * NE);
    float4 w0 = wr[0], w1 = wr[1];
    acc[0] += v * w0.x; acc[1] += v * w0.y; acc[2] += v * w0.z; acc[3] += v * w0.w;
    acc[4] += v * w1.x; acc[5] += v * w1.y; acc[6] += v * w1.z; acc[7] += v * w1.w;
  }
#pragma unroll
  for (int e = 0; e < NE; e++) {
    float v = acc[e];
#pragma unroll
    for (int s = 32; s > 0; s >>= 1) v += __shfl_xor(v, s, 64);
    acc[e] = v;
  }
  int lane = tid & 63, w = tid >> 6;
  if (lane == 0)
#pragma unroll
    for (int e = 0; e < NE; e++) sm.r.red[w][e] = acc[e];
  __syncthreads();
  if (tid == 0) {
    float lg[NE];
#pragma unroll
    for (int e = 0; e < NE; e++)
      lg[e] = sm.r.red[0][e] + sm.r.red[1][e] + sm.r.red[2][e] + sm.r.red[3][e] + bg[e];
    float m = lg[0];
#pragma unroll
    for (int e = 1; e < NE; e++) m = fmaxf(m, lg[e]);
    float p[NE], d = 0.f;
#pragma unroll
    for (int e = 0; e < NE; e++) { p[e] = __expf(lg[e] - m); d += p[e]; }
    float inv = 1.f / d;
    int b0 = 0;
#pragma unroll
    for (int e = 1; e < NE; e++) if (lg[e] > lg[b0]) b0 = e;
    int b1 = (b0 == 0) ? 1 : 0;
#pragma unroll
    for (int e = 0; e < NE; e++) if (e != b0 && lg[e] > lg[b1]) b1 = e;
    eidx2[t * 2 + 0] = b0; gate2[t * 2 + 0] = p[b0] * inv;
    eidx2[t * 2 + 1] = b1; gate2[t * 2 + 1] = p[b1] * inv;
  }
}

// ---------------- per-chunk expert histogram (ballot-based, no atomics) ----------------
__global__ __launch_bounds__(256) void hist_kernel(const int* __restrict__ eidx2,
                                                   int* __restrict__ hist) {
  __shared__ int h[4][NE];
  int b = blockIdx.x, tid = threadIdx.x;
  int lane = tid & 63, w = tid >> 6;
  int t = b * 256 + tid;
  int e0 = eidx2[t * 2], e1 = eidx2[t * 2 + 1];
#pragma unroll
  for (int ee = 0; ee < NE; ee++) {
    unsigned long long m0 = __ballot(e0 == ee);
    unsigned long long m1 = __ballot(e1 == ee);
    if (lane == 0) h[w][ee] = __popcll(m0) + __popcll(m1);
  }
  __syncthreads();
  if (tid < NE) hist[b * NE + tid] = h[0][tid] + h[1][tid] + h[2][tid] + h[3][tid];
}

// ---------------- assign: local scan of hist + deterministic slot assignment ------------
__global__ __launch_bounds__(256) void assign_kernel(
    const int* __restrict__ eidx2, const float* __restrict__ gate2,
    const int* __restrict__ hist, int* __restrict__ cnt,
    int* __restrict__ slot_tok, float* __restrict__ slot_gate, int* __restrict__ tok_slot) {
  __shared__ int wcnt[2][4][NE];   // [item j][wave][expert]
  __shared__ int tot[NE], cbs[NE], cb[NE];
  int b = blockIdx.x;
  int tid = threadIdx.x;
  int lane = tid & 63, w = tid >> 6;
  if (tid < NE) {
    int s = 0, base = 0;
    for (int bb = 0; bb < NCHUNK; bb++) {
      if (bb == b) base = s;
      s += hist[bb * NE + tid];
    }
    tot[tid] = s; cbs[tid] = base;
    if (b == 0) cnt[tid] = s;
  }
  int t = b * 256 + tid;
  int e0 = eidx2[t * 2], e1 = eidx2[t * 2 + 1];
  unsigned long long lt = (1ull << lane) - 1ull;
  int r0 = 0, r1 = 0;
#pragma unroll
  for (int ee = 0; ee < NE; ee++) {
    unsigned long long m0 = __ballot(e0 == ee);
    unsigned long long m1 = __ballot(e1 == ee);
    if (e0 == ee) r0 = __popcll(m0 & lt);
    if (e1 == ee) r1 = __popcll(m1 & lt);
    if (lane == 0) { wcnt[0][w][ee] = __popcll(m0); wcnt[1][w][ee] = __popcll(m1); }
  }
  __syncthreads();
  if (tid == 0) {
    int o = 0;
#pragma unroll
    for (int e = 0; e < NE; e++) { cb[e] = cbs[e] + o; o += tot[e]; }
  }
  __syncthreads();
  int base0 = 0, base1 = 0;
#pragma unroll
  for (int p = 0; p < 8; p++) {
    int c0 = wcnt[p >> 2][p & 3][e0];
    int c1 = wcnt[p >> 2][p & 3][e1];
    if (p < w) base0 += c0;
    if (p < 4 + w) base1 += c1;
  }
  int s0 = cb[e0] + base0 + r0;
  int s1 = cb[e1] + base1 + r1;
  slot_tok[s0] = t; slot_gate[s0] = gate2[t * 2 + 0];
  slot_tok[s1] = t; slot_gate[s1] = gate2[t * 2 + 1];
  tok_slot[t * 2 + 0] = s0;
  tok_slot[t * 2 + 1] = s1;
}

// ---------------- grouped GEMM, 256x256xBK64, 8 waves, counted-vmcnt pipeline ----------
// Y[slot] = bf16(A@We[e] + be[e]) (pre-gate).
// Pipeline: ALL 8 stage issues for the next tile at the TOP of each tile (right after
// the barrier that frees nb); the matching wait is vmcnt(8) at the NEXT tile's top --
// every load gets one full tile (~600-900 cyc) of slack. vmcnt never drains the
// in-flight queue except the last tile.
#define BMG 256
#define BNG 256
#define BKG 64
#define NTG (HD / BKG)
#define EPS 72   // epilogue LDS row stride in shorts

#define STAGEA(b, j) GLDS16(gA[j], &Sm[b][aDst + (j) * 512])
#define STAGEB(b, j) GLDS16(gB + (size_t)((j) * 8) * HD, &Sm[b][bDst + (j) * 512])

#define PHASE(p) do { \
    bf16x8 a00 = *(const bf16x8*)(SA + rdA + (2*(p)+0) * 1024 + s0); \
    bf16x8 a01 = *(const bf16x8*)(SA + rdA + (2*(p)+0) * 1024 + s1); \
    bf16x8 a10 = *(const bf16x8*)(SA + rdA + (2*(p)+1) * 1024 + s0); \
    bf16x8 a11 = *(const bf16x8*)(SA + rdA + (2*(p)+1) * 1024 + s1); \
    __builtin_amdgcn_s_setprio(1); \
    _Pragma("unroll") \
    for (int in = 0; in < 4; in++) { \
      acc[2*(p)][in]   = __builtin_amdgcn_mfma_f32_16x16x32_bf16(a00, b0[in], acc[2*(p)][in], 0, 0, 0); \
      acc[2*(p)][in]   = __builtin_amdgcn_mfma_f32_16x16x32_bf16(a01, b1[in], acc[2*(p)][in], 0, 0, 0); \
      acc[2*(p)+1][in] = __builtin_amdgcn_mfma_f32_16x16x32_bf16(a10, b0[in], acc[2*(p)+1][in], 0, 0, 0); \
      acc[2*(p)+1][in] = __builtin_amdgcn_mfma_f32_16x16x32_bf16(a11, b1[in], acc[2*(p)+1][in], 0, 0, 0); \
    } \
    __builtin_amdgcn_s_setprio(0); \
  } while (0)

__global__ __launch_bounds__(512, 2) void moe_gemm256(
    const unsigned short* __restrict__ xbf, const unsigned short* __restrict__ Wt,
    const int* __restrict__ cnt, const int* __restrict__ slot_tok,
    const float* __restrict__ be, unsigned short* __restrict__ Ybf) {
  // XCD-aware bijective swizzle: 4096 blocks, XCD x owns expert x's 512 tiles.
  int d = blockIdx.x;
  int o = (d & 7) * 512 + (d >> 3);
  int e = o >> 9;
  int nt = (o >> 6) & 7;   // B-panel-major: 64 consecutive tiles share one B panel
  int mt = o & 63;
  int off = 0, c = 0;
#pragma unroll
  for (int i = 0; i < NE; i++) { int ci = cnt[i]; if (i < e) off += ci; if (i == e) c = ci; }
  if (mt * BMG >= c) return;
  int row0 = off + mt * BMG;
  int n0 = nt * BNG;

  __shared__ unsigned short Sm[2][2 * 16384];   // 128 KB

  int tid = threadIdx.x;
  int lane = tid & 63, w = tid >> 6;    // 8 waves
  int wm = w & 1, wn = w >> 1;          // 2 (M) x 4 (N); per-wave out = 128 x 64
  int quad = lane >> 4, l16 = lane & 15;

  // ---- staging setup: per-lane pre-swizzled global source ----
  int lrow = lane >> 3;                       // row within 8-row issue
  int kswz = ((lane & 7) ^ lrow) * 8;         // shorts: logical k-slot for phys slot lane&7
  const unsigned short* gA[4];
#pragma unroll
  for (int j = 0; j < 4; j++) {
    int sl = min(row0 + w * 32 + j * 8 + lrow, NSLOT - 1);
    gA[j] = xbf + (size_t)slot_tok[sl] * HD + kswz;
  }
  const unsigned short* gB = Wt + ((size_t)e * HD + n0 + w * 32 + lrow) * HD + kswz;
  int aDst = (w * 32) * 64;                   // shorts; + j*512
  int bDst = 16384 + (w * 32) * 64;

  // ---- fragment read offsets (shorts), swizzled ----
  int rdA = (wm * 128 + l16) * 64;            // + im*1024 + slot
  int rdB = 16384 + (wn * 64 + l16) * 64;     // + in*1024 + slot
  int s0 = ((quad) ^ (l16 & 7)) * 8;          // ks=0
  int s1 = ((4 + quad) ^ (l16 & 7)) * 8;      // ks=1

  f32x4 acc[8][4] = {};

  // prologue: stage K-tile 0 into buf 0
#pragma unroll
  for (int j = 0; j < 4; j++) STAGEA(0, j);
#pragma unroll
  for (int j = 0; j < 4; j++) STAGEB(0, j);
#pragma unroll
  for (int j = 0; j < 4; j++) gA[j] += BKG;
  gB += BKG;

  for (int kt = 0; kt < NTG; ++kt) {
    const int buf = kt & 1, nb = buf ^ 1;
    const unsigned short* SA = &Sm[buf][0];
    const bool pf = (kt < NTG - 1);
    __builtin_amdgcn_s_barrier();              // all waves done reading Sm[nb]
    __builtin_amdgcn_sched_barrier(0);
    if (pf) {
      // issue ALL next-tile stages now -> full-tile slack before their wait
      STAGEA(nb, 0); STAGEA(nb, 1); STAGEA(nb, 2); STAGEA(nb, 3);
      STAGEB(nb, 0); STAGEB(nb, 1); STAGEB(nb, 2); STAGEB(nb, 3);
#pragma unroll
      for (int j = 0; j < 4; j++) gA[j] += BKG;
      gB += BKG;
      __builtin_amdgcn_sched_barrier(0);
      asm volatile("s_waitcnt vmcnt(8)" ::: "memory");   // drain buf's 8 (issued 1 tile ago)
    } else {
      asm volatile("s_waitcnt vmcnt(0)" ::: "memory");
    }
    __builtin_amdgcn_sched_barrier(0);
    __builtin_amdgcn_s_barrier();              // buf fully staged by all waves
    __builtin_amdgcn_sched_barrier(0);

    bf16x8 b0[4], b1[4];
#pragma unroll
    for (int in = 0; in < 4; in++) {
      b0[in] = *(const bf16x8*)(SA + rdB + in * 1024 + s0);
      b1[in] = *(const bf16x8*)(SA + rdB + in * 1024 + s1);
    }
    PHASE(0);
    PHASE(1);
    PHASE(2);
    PHASE(3);
  }

  // ---- epilogue: per-wave LDS transpose -> coalesced 128B Y stores ----
  // reg regions are wave-private; the kt=NTG-1 barriers guarantee no wave still reads
  // Sm[0] (last tile reads Sm[1]). Within-wave ds_write->ds_read ordering is handled
  // by compiler-inserted lgkmcnt -> no block barriers needed here.
  float biasr[4];
#pragma unroll
  for (int in = 0; in < 4; in++)
    biasr[in] = be[e * HD + n0 + wn * 64 + in * 16 + l16];

  unsigned short* reg = &Sm[0][0] + w * (16 * EPS);   // 8 waves x 2.25 KB
  int rrow = lane >> 2;
  int rcol = (lane & 3) * 16;
#pragma unroll
  for (int im = 0; im < 8; im++) {
#pragma unroll
    for (int in = 0; in < 4; in++)
#pragma unroll
      for (int r = 0; r < 4; r++)
        reg[(quad * 4 + r) * EPS + in * 16 + l16] = f2bf(acc[im][in][r] + biasr[in]);
    int gr = mt * BMG + wm * 128 + im * 16 + rrow;
    if (gr < c) {
      bf16x8 v0 = *(const bf16x8*)(reg + rrow * EPS + rcol);
      bf16x8 v1 = *(const bf16x8*)(reg + rrow * EPS + rcol + 8);
      unsigned short* dst = Ybf + (size_t)(off + gr) * HD + n0 + wn * 64 + rcol;
      *(bf16x8*)dst = v0;
      *(bf16x8*)(dst + 8) = v1;
    }
  }
}

// ---------------- combine: out[t] = g0*Y[s0] + g1*Y[s1] ----------------
__global__ __launch_bounds__(256) void combine_kernel(
    const unsigned short* __restrict__ Ybf, const int* __restrict__ tok_slot,
    const float* __restrict__ slot_gate, float* __restrict__ out) {
  int c8 = threadIdx.x * 8;
#pragma unroll
  for (int i = 0; i < 4; i++) {
    int t = blockIdx.x * 4 + i;
    int s0 = tok_slot[t * 2], s1 = tok_slot[t * 2 + 1];
    float g0 = slot_gate[s0], g1 = slot_gate[s1];
    union { bf16x8 v; unsigned short s[8]; } y0, y1;
    y0.v = *(const bf16x8*)(Ybf + (size_t)s0 * HD + c8);
    y1.v = *(const bf16x8*)(Ybf + (size_t)s1 * HD + c8);
    float4 o0, o1;
    o0.x = g0 * bf2f(y0.s[0]) + g1 * bf2f(y1.s[0]);
    o0.y = g0 * bf2f(y0.s[1]) + g1 * bf2f(y1.s[1]);
    o0.z = g0 * bf2f(y0.s[2]) + g1 * bf2f(y1.s[2]);
    o0.w = g0 * bf2f(y0.s[3]) + g1 * bf2f(y1.s[3]);
    o1.x = g0 * bf2f(y0.s[4]) + g1 * bf2f(y1.s[4]);
    o1.y = g0 * bf2f(y0.s[5]) + g1 * bf2f(y1.s[5]);
    o1.z = g0 * bf2f(y0.s[6]) + g1 * bf2f(y1.s[6]);
    o1.w = g0 * bf2f(y0.s[7]) + g1 * bf2f(y1.s[7]);
    float4* dst = (float4*)(out + (size_t)t * HD + c8);
    dst[0] = o0;
    dst[1] = o1;
  }
}

extern "C" void kernel_launch(void* const* d_in, const int* in_sizes, int n_in,
                              void* d_out, int out_size, void* d_ws, size_t ws_size,
                              hipStream_t stream) {
  const float* x  = (const float*)d_in[0];
  const float* Wg = (const float*)d_in[1];
  const float* bg = (const float*)d_in[2];
  const float* We = (const float*)d_in[3];
  const float* be = (const float*)d_in[4];
  float* out = (float*)d_out;

  char* ws = (char*)d_ws;
  int* cnt        = (int*)ws;                          // 8 ints
  int* hist       = (int*)(ws + 256);                  // NCHUNK*NE ints (1 KB)
  int* eidx2       = (int*)(ws + 4096);
  float* gate2     = (float*)(ws + 4096 + NSLOT * 4);
  int* slot_tok    = (int*)(ws + 4096 + 2 * NSLOT * 4);
  float* slot_gate = (float*)(ws + 4096 + 3 * NSLOT * 4);
  int* tok_slot    = (int*)(ws + 4096 + 4 * NSLOT * 4);
  unsigned short* xbf = (unsigned short*)(ws + 8192 + 5 * NSLOT * 4);  // TOK x HD bf16 (33.5 MB)
  unsigned short* Wt  = xbf + (size_t)TOK * HD;                        // E x HD x HD bf16 (67 MB)
  unsigned short* Ybf = Wt + (size_t)NE * HD * HD;                     // NSLOT x HD bf16 (67 MB)

  route_wconv_kernel<<<2 * TOK, 256, 0, stream>>>(x, Wg, bg, We, eidx2, gate2, xbf, Wt);
  hist_kernel<<<NCHUNK, 256, 0, stream>>>(eidx2, hist);
  assign_kernel<<<NCHUNK, 256, 0, stream>>>(eidx2, gate2, hist, cnt, slot_tok, slot_gate, tok_slot);
  moe_gemm256<<<NE * 64 * 8, 512, 0, stream>>>(xbf, Wt, cnt, slot_tok, be, Ybf);
  combine_kernel<<<TOK / 4, 256, 0, stream>>>(Ybf, tok_slot, slot_gate, out);
}

// Round 5
// 450.247 us; speedup vs baseline: 1.0570x; 1.0570x over previous
//
#include <hip/hip_runtime.h>
#include <hip/hip_bf16.h>

#define TOK 8192      // B*S tokens
#define HD 2048       // hidden
#define NE 8          // experts
#define KTOP 2
#define NSLOT (TOK * KTOP)
#define NCHUNK (TOK / 256)   // 32 routing chunks

typedef __attribute__((ext_vector_type(8))) short bf16x8;
typedef __attribute__((ext_vector_type(4))) float f32x4;

// async global->LDS, 16B per lane, dest = wave-uniform base + lane*16
#define GLDS16(g, l) __builtin_amdgcn_global_load_lds( \
    (const __attribute__((address_space(1))) void*)(g), \
    (__attribute__((address_space(3))) void*)(l), 16, 0, 0)

// round-to-nearest-even fp32 -> bf16 bits
__device__ __forceinline__ unsigned short f2bf(float f) {
  union { float f; unsigned u; } v; v.f = f;
  unsigned r = v.u + 0x7fffu + ((v.u >> 16) & 1u);
  return (unsigned short)(r >> 16);
}
__device__ __forceinline__ float bf2f(unsigned short b) {
  union { unsigned u; float f; } v; v.u = ((unsigned)b) << 16;
  return v.f;
}

// ---------------- fused: router (even bids) + weight transpose-convert (odd bids) ------
__global__ __launch_bounds__(256) void route_wconv_kernel(
    const float* __restrict__ x, const float* __restrict__ Wg, const float* __restrict__ bg,
    const float* __restrict__ We,
    int* __restrict__ eidx2, float* __restrict__ gate2,
    unsigned short* __restrict__ xbf, unsigned short* __restrict__ Wt) {
  __shared__ union {
    struct { float xs[HD]; float red[4][NE]; } r;   // routex: 8.3 KB
    float tile[64][65];                             // wconv: 16.6 KB
  } sm;
  int bid = blockIdx.x;
  int tid = threadIdx.x;

  if (bid & 1) {
    // ---- wconv: We[e][k][n] -> Wt[e][n][k] bf16, 64x64 tile ----
    int i = bid >> 1;
    int e = i >> 10;                  // 1024 tiles per expert (32x32)
    int rem = i & 1023;
    int k0 = (rem >> 5) * 64, n0 = (rem & 31) * 64;
    const float* src = We + ((size_t)e * HD + k0) * HD + n0;
#pragma unroll
    for (int it = 0; it < 4; it++) {
      int f = tid + it * 256;
      int r = f >> 4, c4 = (f & 15) * 4;
      float4 v = *(const float4*)(src + (size_t)r * HD + c4);
      sm.tile[r][c4 + 0] = v.x; sm.tile[r][c4 + 1] = v.y;
      sm.tile[r][c4 + 2] = v.z; sm.tile[r][c4 + 3] = v.w;
    }
    __syncthreads();
    unsigned short* dst = Wt + ((size_t)e * HD + n0) * HD + k0;
#pragma unroll
    for (int it = 0; it < 2; it++) {
      int s = tid + it * 256;
      int n = s >> 3, k8 = (s & 7) * 8;
      union { bf16x8 v; unsigned short us[8]; } o;
#pragma unroll
      for (int j = 0; j < 8; j++) o.us[j] = f2bf(sm.tile[k8 + j][n]);
      *(bf16x8*)(dst + (size_t)n * HD + k8) = o.v;
    }
    return;
  }

  // ---- routex: x->bf16 + router (logits, softmax, top-2). No atomics. ----
  int t = bid >> 1;
  const float4* xr = (const float4*)(x + (size_t)t * HD);
  float4 a = xr[tid * 2], b = xr[tid * 2 + 1];
  union { bf16x8 v; unsigned short s[8]; } o;
  o.s[0] = f2bf(a.x); o.s[1] = f2bf(a.y); o.s[2] = f2bf(a.z); o.s[3] = f2bf(a.w);
  o.s[4] = f2bf(b.x); o.s[5] = f2bf(b.y); o.s[6] = f2bf(b.z); o.s[7] = f2bf(b.w);
  *(bf16x8*)(xbf + (size_t)t * HD + tid * 8) = o.v;
  *(float4*)(sm.r.xs + tid * 8) = a;
  *(float4*)(sm.r.xs + tid * 8 + 4) = b;
  __syncthreads();

  float acc[NE];
#pragma unroll
  for (int e = 0; e < NE; e++) acc[e] = 0.f;
#pragma unroll
  for (int i = 0; i < HD / 256; i++) {
    int k = tid + i * 256;               // consecutive lanes -> consecutive Wg rows
    float v = sm.r.xs[k];
    const float4* wr = (const float4*)(Wg + (size_t)k * NE);
    float4 w0 = wr[0], w1 = wr[1];
    acc[0] += v * w0.x; acc[1] += v * w0.y; acc[2] += v * w0.z; acc[3] += v * w0.w;
    acc[4] += v * w1.x; acc[5] += v * w1.y; acc[6] += v * w1.z; acc[7] += v * w1.w;
  }
#pragma unroll
  for (int e = 0; e < NE; e++) {
    float v = acc[e];
#pragma unroll
    for (int s = 32; s > 0; s >>= 1) v += __shfl_xor(v, s, 64);
    acc[e] = v;
  }
  int lane = tid & 63, w = tid >> 6;
  if (lane == 0)
#pragma unroll
    for (int e = 0; e < NE; e++) sm.r.red[w][e] = acc[e];
  __syncthreads();
  if (tid == 0) {
    float lg[NE];
#pragma unroll
    for (int e = 0; e < NE; e++)
      lg[e] = sm.r.red[0][e] + sm.r.red[1][e] + sm.r.red[2][e] + sm.r.red[3][e] + bg[e];
    float m = lg[0];
#pragma unroll
    for (int e = 1; e < NE; e++) m = fmaxf(m, lg[e]);
    float p[NE], d = 0.f;
#pragma unroll
    for (int e = 0; e < NE; e++) { p[e] = __expf(lg[e] - m); d += p[e]; }
    float inv = 1.f / d;
    int b0 = 0;
#pragma unroll
    for (int e = 1; e < NE; e++) if (lg[e] > lg[b0]) b0 = e;
    int b1 = (b0 == 0) ? 1 : 0;
#pragma unroll
    for (int e = 0; e < NE; e++) if (e != b0 && lg[e] > lg[b1]) b1 = e;
    eidx2[t * 2 + 0] = b0; gate2[t * 2 + 0] = p[b0] * inv;
    eidx2[t * 2 + 1] = b1; gate2[t * 2 + 1] = p[b1] * inv;
  }
}

// ---------------- per-chunk expert histogram (ballot-based, no atomics) ----------------
__global__ __launch_bounds__(256) void hist_kernel(const int* __restrict__ eidx2,
                                                   int* __restrict__ hist) {
  __shared__ int h[4][NE];
  int b = blockIdx.x, tid = threadIdx.x;
  int lane = tid & 63, w = tid >> 6;
  int t = b * 256 + tid;
  int e0 = eidx2[t * 2], e1 = eidx2[t * 2 + 1];
#pragma unroll
  for (int ee = 0; ee < NE; ee++) {
    unsigned long long m0 = __ballot(e0 == ee);
    unsigned long long m1 = __ballot(e1 == ee);
    if (lane == 0) h[w][ee] = __popcll(m0) + __popcll(m1);
  }
  __syncthreads();
  if (tid < NE) hist[b * NE + tid] = h[0][tid] + h[1][tid] + h[2][tid] + h[3][tid];
}

// ---------------- assign: local scan of hist + deterministic slot assignment ------------
__global__ __launch_bounds__(256) void assign_kernel(
    const int* __restrict__ eidx2, const float* __restrict__ gate2,
    const int* __restrict__ hist, int* __restrict__ cnt,
    int* __restrict__ slot_tok, float* __restrict__ slot_gate, int* __restrict__ tok_slot) {
  __shared__ int wcnt[2][4][NE];   // [item j][wave][expert]
  __shared__ int tot[NE], cbs[NE], cb[NE];
  int b = blockIdx.x;
  int tid = threadIdx.x;
  int lane = tid & 63, w = tid >> 6;
  if (tid < NE) {
    int s = 0, base = 0;
    for (int bb = 0; bb < NCHUNK; bb++) {
      if (bb == b) base = s;
      s += hist[bb * NE + tid];
    }
    tot[tid] = s; cbs[tid] = base;
    if (b == 0) cnt[tid] = s;
  }
  int t = b * 256 + tid;
  int e0 = eidx2[t * 2], e1 = eidx2[t * 2 + 1];
  unsigned long long lt = (1ull << lane) - 1ull;
  int r0 = 0, r1 = 0;
#pragma unroll
  for (int ee = 0; ee < NE; ee++) {
    unsigned long long m0 = __ballot(e0 == ee);
    unsigned long long m1 = __ballot(e1 == ee);
    if (e0 == ee) r0 = __popcll(m0 & lt);
    if (e1 == ee) r1 = __popcll(m1 & lt);
    if (lane == 0) { wcnt[0][w][ee] = __popcll(m0); wcnt[1][w][ee] = __popcll(m1); }
  }
  __syncthreads();
  if (tid == 0) {
    int o = 0;
#pragma unroll
    for (int e = 0; e < NE; e++) { cb[e] = cbs[e] + o; o += tot[e]; }
  }
  __syncthreads();
  int base0 = 0, base1 = 0;
#pragma unroll
  for (int p = 0; p < 8; p++) {
    int c0 = wcnt[p >> 2][p & 3][e0];
    int c1 = wcnt[p >> 2][p & 3][e1];
    if (p < w) base0 += c0;
    if (p < 4 + w) base1 += c1;
  }
  int s0 = cb[e0] + base0 + r0;
  int s1 = cb[e1] + base1 + r1;
  slot_tok[s0] = t; slot_gate[s0] = gate2[t * 2 + 0];
  slot_tok[s1] = t; slot_gate[s1] = gate2[t * 2 + 1];
  tok_slot[t * 2 + 0] = s0;
  tok_slot[t * 2 + 1] = s1;
}

// ---------------- grouped GEMM, 256x256xBK64, 8 waves, counted-vmcnt pipeline ----------
// Y[slot] = bf16(A@We[e] + be[e]) (pre-gate).
// Schedule (R3/R4 synthesis): stage issues SPREAD across phases (overlap with MFMA),
// shifted one phase EARLY so the youngest load gets a full empty phase + barrier of
// slack before its vmcnt(2) wait. Issue map: top:{A0,A1} P0:{A2,A3} P1:{B0,B1}
// P2:{B2,B3} P3:{}. vmcnt never drains in-flight prefetch except the last tile.
#define BMG 256
#define BNG 256
#define BKG 64
#define NTG (HD / BKG)
#define EPS 72   // epilogue LDS row stride in shorts

#define STAGEA(b, j) GLDS16(gA[j], &Sm[b][aDst + (j) * 512])
#define STAGEB(b, j) GLDS16(gB + (size_t)((j) * 8) * HD, &Sm[b][bDst + (j) * 512])

#define PHASE(p, STAGES) do { \
    bf16x8 a00 = *(const bf16x8*)(SA + rdA + (2*(p)+0) * 1024 + s0); \
    bf16x8 a01 = *(const bf16x8*)(SA + rdA + (2*(p)+0) * 1024 + s1); \
    bf16x8 a10 = *(const bf16x8*)(SA + rdA + (2*(p)+1) * 1024 + s0); \
    bf16x8 a11 = *(const bf16x8*)(SA + rdA + (2*(p)+1) * 1024 + s1); \
    STAGES; \
    __builtin_amdgcn_s_setprio(1); \
    _Pragma("unroll") \
    for (int in = 0; in < 4; in++) { \
      acc[2*(p)][in]   = __builtin_amdgcn_mfma_f32_16x16x32_bf16(a00, b0[in], acc[2*(p)][in], 0, 0, 0); \
      acc[2*(p)][in]   = __builtin_amdgcn_mfma_f32_16x16x32_bf16(a01, b1[in], acc[2*(p)][in], 0, 0, 0); \
      acc[2*(p)+1][in] = __builtin_amdgcn_mfma_f32_16x16x32_bf16(a10, b0[in], acc[2*(p)+1][in], 0, 0, 0); \
      acc[2*(p)+1][in] = __builtin_amdgcn_mfma_f32_16x16x32_bf16(a11, b1[in], acc[2*(p)+1][in], 0, 0, 0); \
    } \
    __builtin_amdgcn_s_setprio(0); \
  } while (0)

__global__ __launch_bounds__(512, 2) void moe_gemm256(
    const unsigned short* __restrict__ xbf, const unsigned short* __restrict__ Wt,
    const int* __restrict__ cnt, const int* __restrict__ slot_tok,
    const float* __restrict__ be, unsigned short* __restrict__ Ybf) {
  // XCD-aware bijective swizzle: 4096 blocks, XCD x owns expert x's 512 tiles.
  int d = blockIdx.x;
  int o = (d & 7) * 512 + (d >> 3);
  int e = o >> 9;
  int nt = (o >> 6) & 7;   // B-panel-major: 64 consecutive tiles share one B panel
  int mt = o & 63;
  int off = 0, c = 0;
#pragma unroll
  for (int i = 0; i < NE; i++) { int ci = cnt[i]; if (i < e) off += ci; if (i == e) c = ci; }
  if (mt * BMG >= c) return;
  int row0 = off + mt * BMG;
  int n0 = nt * BNG;

  __shared__ unsigned short Sm[2][2 * 16384];   // 128 KB

  int tid = threadIdx.x;
  int lane = tid & 63, w = tid >> 6;    // 8 waves
  int wm = w & 1, wn = w >> 1;          // 2 (M) x 4 (N); per-wave out = 128 x 64
  int quad = lane >> 4, l16 = lane & 15;

  // ---- staging setup: per-lane pre-swizzled global source ----
  int lrow = lane >> 3;                       // row within 8-row issue
  int kswz = ((lane & 7) ^ lrow) * 8;         // shorts: logical k-slot for phys slot lane&7
  const unsigned short* gA[4];
#pragma unroll
  for (int j = 0; j < 4; j++) {
    int sl = min(row0 + w * 32 + j * 8 + lrow, NSLOT - 1);
    gA[j] = xbf + (size_t)slot_tok[sl] * HD + kswz;
  }
  const unsigned short* gB = Wt + ((size_t)e * HD + n0 + w * 32 + lrow) * HD + kswz;
  int aDst = (w * 32) * 64;                   // shorts; + j*512
  int bDst = 16384 + (w * 32) * 64;

  // ---- fragment read offsets (shorts), swizzled ----
  int rdA = (wm * 128 + l16) * 64;            // + im*1024 + slot
  int rdB = 16384 + (wn * 64 + l16) * 64;     // + in*1024 + slot
  int s0 = ((quad) ^ (l16 & 7)) * 8;          // ks=0
  int s1 = ((4 + quad) ^ (l16 & 7)) * 8;      // ks=1

  f32x4 acc[8][4] = {};

  // prologue: stage K-tile 0 into buf 0
#pragma unroll
  for (int j = 0; j < 4; j++) STAGEA(0, j);
#pragma unroll
  for (int j = 0; j < 4; j++) STAGEB(0, j);
#pragma unroll
  for (int j = 0; j < 4; j++) gA[j] += BKG;
  gB += BKG;

  for (int kt = 0; kt < NTG; ++kt) {
    const int buf = kt & 1, nb = buf ^ 1;
    const unsigned short* SA = &Sm[buf][0];
    const bool pf = (kt < NTG - 1);
    __builtin_amdgcn_s_barrier();              // all waves done reading Sm[nb]
    __builtin_amdgcn_sched_barrier(0);
    if (pf) { STAGEA(nb, 0); STAGEA(nb, 1); }
    __builtin_amdgcn_sched_barrier(0);
    if (pf) asm volatile("s_waitcnt vmcnt(2)" ::: "memory");   // drain buf's 8, keep 2
    else    asm volatile("s_waitcnt vmcnt(0)" ::: "memory");
    __builtin_amdgcn_sched_barrier(0);
    __builtin_amdgcn_s_barrier();              // buf fully staged by all waves
    __builtin_amdgcn_sched_barrier(0);

    bf16x8 b0[4], b1[4];
#pragma unroll
    for (int in = 0; in < 4; in++) {
      b0[in] = *(const bf16x8*)(SA + rdB + in * 1024 + s0);
      b1[in] = *(const bf16x8*)(SA + rdB + in * 1024 + s1);
    }
    PHASE(0, if (pf) { STAGEA(nb, 2); STAGEA(nb, 3); });
    PHASE(1, if (pf) { STAGEB(nb, 0); STAGEB(nb, 1); });
    PHASE(2, if (pf) { STAGEB(nb, 2); STAGEB(nb, 3); });
    PHASE(3, (void)0);
    if (pf) {
#pragma unroll
      for (int j = 0; j < 4; j++) gA[j] += BKG;
      gB += BKG;
    }
  }

  // ---- epilogue: per-wave LDS transpose -> coalesced 128B Y stores ----
  // reg regions are wave-private; last tile's barriers guarantee no wave still reads
  // Sm[0]. Within-wave ds_write->ds_read ordering handled by compiler lgkmcnt.
  float biasr[4];
#pragma unroll
  for (int in = 0; in < 4; in++)
    biasr[in] = be[e * HD + n0 + wn * 64 + in * 16 + l16];

  unsigned short* reg = &Sm[0][0] + w * (16 * EPS);   // 8 waves x 2.25 KB
  int rrow = lane >> 2;
  int rcol = (lane & 3) * 16;
#pragma unroll
  for (int im = 0; im < 8; im++) {
#pragma unroll
    for (int in = 0; in < 4; in++)
#pragma unroll
      for (int r = 0; r < 4; r++)
        reg[(quad * 4 + r) * EPS + in * 16 + l16] = f2bf(acc[im][in][r] + biasr[in]);
    int gr = mt * BMG + wm * 128 + im * 16 + rrow;
    if (gr < c) {
      bf16x8 v0 = *(const bf16x8*)(reg + rrow * EPS + rcol);
      bf16x8 v1 = *(const bf16x8*)(reg + rrow * EPS + rcol + 8);
      unsigned short* dst = Ybf + (size_t)(off + gr) * HD + n0 + wn * 64 + rcol;
      *(bf16x8*)dst = v0;
      *(bf16x8*)(dst + 8) = v1;
    }
  }
}

// ---------------- combine: out[t] = g0*Y[s0] + g1*Y[s1] ----------------
__global__ __launch_bounds__(256) void combine_kernel(
    const unsigned short* __restrict__ Ybf, const int* __restrict__ tok_slot,
    const float* __restrict__ slot_gate, float* __restrict__ out) {
  int c8 = threadIdx.x * 8;
#pragma unroll
  for (int i = 0; i < 8; i++) {
    int t = blockIdx.x * 8 + i;
    int s0 = tok_slot[t * 2], s1 = tok_slot[t * 2 + 1];
    float g0 = slot_gate[s0], g1 = slot_gate[s1];
    union { bf16x8 v; unsigned short s[8]; } y0, y1;
    y0.v = *(const bf16x8*)(Ybf + (size_t)s0 * HD + c8);
    y1.v = *(const bf16x8*)(Ybf + (size_t)s1 * HD + c8);
    float4 o0, o1;
    o0.x = g0 * bf2f(y0.s[0]) + g1 * bf2f(y1.s[0]);
    o0.y = g0 * bf2f(y0.s[1]) + g1 * bf2f(y1.s[1]);
    o0.z = g0 * bf2f(y0.s[2]) + g1 * bf2f(y1.s[2]);
    o0.w = g0 * bf2f(y0.s[3]) + g1 * bf2f(y1.s[3]);
    o1.x = g0 * bf2f(y0.s[4]) + g1 * bf2f(y1.s[4]);
    o1.y = g0 * bf2f(y0.s[5]) + g1 * bf2f(y1.s[5]);
    o1.z = g0 * bf2f(y0.s[6]) + g1 * bf2f(y1.s[6]);
    o1.w = g0 * bf2f(y0.s[7]) + g1 * bf2f(y1.s[7]);
    float4* dst = (float4*)(out + (size_t)t * HD + c8);
    dst[0] = o0;
    dst[1] = o1;
  }
}

extern "C" void kernel_launch(void* const* d_in, const int* in_sizes, int n_in,
                              void* d_out, int out_size, void* d_ws, size_t ws_size,
                              hipStream_t stream) {
  const float* x  = (const float*)d_in[0];
  const float* Wg = (const float*)d_in[1];
  const float* bg = (const float*)d_in[2];
  const float* We = (const float*)d_in[3];
  const float* be = (const float*)d_in[4];
  float* out = (float*)d_out;

  char* ws = (char*)d_ws;
  int* cnt        = (int*)ws;                          // 8 ints
  int* hist       = (int*)(ws + 256);                  // NCHUNK*NE ints (1 KB)
  int* eidx2       = (int*)(ws + 4096);
  float* gate2     = (float*)(ws + 4096 + NSLOT * 4);
  int* slot_tok    = (int*)(ws + 4096 + 2 * NSLOT * 4);
  float* slot_gate = (float*)(ws + 4096 + 3 * NSLOT * 4);
  int* tok_slot    = (int*)(ws + 4096 + 4 * NSLOT * 4);
  unsigned short* xbf = (unsigned short*)(ws + 8192 + 5 * NSLOT * 4);  // TOK x HD bf16 (33.5 MB)
  unsigned short* Wt  = xbf + (size_t)TOK * HD;                        // E x HD x HD bf16 (67 MB)
  unsigned short* Ybf = Wt + (size_t)NE * HD * HD;                     // NSLOT x HD bf16 (67 MB)

  route_wconv_kernel<<<2 * TOK, 256, 0, stream>>>(x, Wg, bg, We, eidx2, gate2, xbf, Wt);
  hist_kernel<<<NCHUNK, 256, 0, stream>>>(eidx2, hist);
  assign_kernel<<<NCHUNK, 256, 0, stream>>>(eidx2, gate2, hist, cnt, slot_tok, slot_gate, tok_slot);
  moe_gemm256<<<NE * 64 * 8, 512, 0, stream>>>(xbf, Wt, cnt, slot_tok, be, Ybf);
  combine_kernel<<<TOK / 8, 256, 0, stream>>>(Ybf, tok_slot, slot_gate, out);
}